// Round 15
// baseline (117.519 us; speedup 1.0000x reference)
//
#include <hip/hip_runtime.h>

// Problem constants (reference: clip_embeddings [32, 1024, 512] fp32)
#define BB 32
#define NN 1024
#define DD 512
#define KK 512            // k = N * 0.5
#define EPSF 1e-8f

#define CPB1 64           // k1 blocks per batch
#define TPW1 4            // k1 tokens per wave (8 float4 in flight, ~58 VGPR)
#define CPB2 32           // k2 blocks per batch
#define TPB2 32           // k2 tokens per block
#define TPW2 8            // k2 tokens per wave

__device__ __forceinline__ float wsumf(float v) {
#pragma unroll
    for (int m = 1; m < 64; m <<= 1) v += __shfl_xor(v, m, 64);
    return v;
}
__device__ __forceinline__ int wsumi(int v) {
#pragma unroll
    for (int m = 1; m < 64; m <<= 1) v += __shfl_xor(v, m, 64);
    return v;
}

// K1 (occupancy-tuned): norms + per-block unit-vector partial sums.
// grid = BB*CPB1 = 2048 blocks, 256 threads (4 waves), 4 tokens/wave ->
// 16 tokens/block. Lighter waves (8 float4 = 32 data VGPRs) +
// __launch_bounds__(256,6) -> 6 blocks/CU = 24 waves/CU for the HBM-cold
// 64 MB pass (R11 ran 16 waves/CU at ~3 TB/s; this should reach ~4.5+).
// Spill tripwire: k1 WRITE_SIZE must stay ~4.3 MB (partials+norms).
__global__ __launch_bounds__(256, 6) void k1_norms_partials(const float* __restrict__ x,
                                                            float* __restrict__ norms,
                                                            float* __restrict__ partials) {
    int blk = blockIdx.x;
    int b = blk >> 6, c = blk & 63;
    int tid = threadIdx.x, wave = tid >> 6, lane = tid & 63;
    int tok0 = c * 16 + wave * TPW1;
    const float* base = x + (size_t)(b * NN + tok0) * DD;

    float4 xs0[TPW1], xs1[TPW1];
#pragma unroll
    for (int t = 0; t < TPW1; ++t) {
        const float4* p = reinterpret_cast<const float4*>(base + (size_t)t * DD) + lane * 2;
        xs0[t] = p[0];
        xs1[t] = p[1];
    }

    float4 a0 = {0, 0, 0, 0}, a1 = {0, 0, 0, 0};
#pragma unroll
    for (int t = 0; t < TPW1; ++t) {
        float4 v0 = xs0[t], v1 = xs1[t];
        float ssq = v0.x * v0.x + v0.y * v0.y + v0.z * v0.z + v0.w * v0.w +
                    v1.x * v1.x + v1.y * v1.y + v1.z * v1.z + v1.w * v1.w;
        ssq = wsumf(ssq);
        float nrm = sqrtf(ssq);
        if (lane == 0) norms[b * NN + tok0 + t] = nrm;
        float inv = 1.0f / fmaxf(nrm, EPSF);
        a0.x += v0.x * inv; a0.y += v0.y * inv; a0.z += v0.z * inv; a0.w += v0.w * inv;
        a1.x += v1.x * inv; a1.y += v1.y * inv; a1.z += v1.z * inv; a1.w += v1.w * inv;
    }

    __shared__ float red[4][DD];
    {
        float4* rr = reinterpret_cast<float4*>(&red[wave][lane * 8]);
        rr[0] = a0; rr[1] = a1;
    }
    __syncthreads();
#pragma unroll
    for (int i = 0; i < 2; ++i) {
        int d = tid + i * 256;
        partials[(size_t)blk * DD + d] = red[0][d] + red[1][d] + red[2][d] + red[3][d];
    }
}

// K2 (R11-proven; only the partial-reduce bound changes 32->64): per-block
// reduce of the batch's 64 partials -> sum_unit (LDS, fixed order =
// deterministic; L2-broadcast), then scores for this block's 32 tokens.
// c==0 blocks zero out[b] (stream order precedes k34's atomics).
__global__ __launch_bounds__(256, 4) void k2_scores(const float* __restrict__ x,
                                                    const float* __restrict__ norms,
                                                    const float* __restrict__ partials,
                                                    float* __restrict__ scores,
                                                    float* __restrict__ out) {
    int blk = blockIdx.x;
    int b = blk / CPB2, c = blk % CPB2;
    int tid = threadIdx.x, wave = tid >> 6, lane = tid & 63;

    __shared__ __align__(16) float su_lds[DD];
    {
        float s0 = 0.f, s1 = 0.f;
        const float* pb = partials + (size_t)b * CPB1 * DD;
#pragma unroll 8
        for (int cc = 0; cc < CPB1; ++cc) {         // fixed order: deterministic
            s0 += pb[(size_t)cc * DD + tid];
            s1 += pb[(size_t)cc * DD + tid + 256];
        }
        su_lds[tid] = s0;
        su_lds[tid + 256] = s1;
    }
    if (c == 0) {                                    // zero out[b] for k34
        out[b * DD + tid] = 0.f;
        out[b * DD + tid + 256] = 0.f;
    }
    __syncthreads();

    float4 su0 = reinterpret_cast<const float4*>(&su_lds[lane * 8])[0];
    float4 su1 = reinterpret_cast<const float4*>(&su_lds[lane * 8])[1];

    int tok0 = c * TPB2 + wave * TPW2;
    const float* base = x + (size_t)(b * NN + tok0) * DD;
#pragma unroll
    for (int t = 0; t < TPW2; ++t) {
        const float4* p = reinterpret_cast<const float4*>(base + (size_t)t * DD) + lane * 2;
        float4 v0 = p[0], v1 = p[1];
        float d = v0.x * su0.x + v0.y * su0.y + v0.z * su0.z + v0.w * su0.w +
                  v1.x * su1.x + v1.y * su1.y + v1.z * su1.z + v1.w * su1.w;
        d = wsumf(d);
        if (lane == 0) {
            float nrm = norms[b * NN + tok0 + t];
            scores[b * NN + tok0 + t] = d / (fmaxf(nrm, EPSF) * (float)NN);
        }
    }
}

// K34 (R11-proven, byte-for-byte): fused rank-count selection + gather.
// grid = BB*32 blocks (4/CU -> 16 waves/CU), 256 threads (4 waves,
// 8 tokens/wave). Rank-count reproduces lax.top_k's stable tie-break
// (greater, or equal with lower index); wave-parallel count via float4 LDS
// reads + wsumi. Block reduce; 32 atomicAdds/element (out zeroed by k2).
__global__ __launch_bounds__(256, 4) void k34_select_gather(const float* __restrict__ x,
                                                            const float* __restrict__ scores,
                                                            float* __restrict__ out) {
    int blk = blockIdx.x;
    int b = blk >> 5, g = blk & 31;
    int tid = threadIdx.x, wave = tid >> 6, lane = tid & 63;

    __shared__ __align__(16) float s_lds[NN];
    reinterpret_cast<float4*>(s_lds)[tid] =
        reinterpret_cast<const float4*>(scores + b * NN)[tid];   // 256*4 = 1024
    __syncthreads();

    const float4* sv = reinterpret_cast<const float4*>(s_lds);
    float4 c0 = {0, 0, 0, 0}, c1 = {0, 0, 0, 0};
    int tok0 = g * 32 + wave * 8;

#pragma unroll
    for (int t = 0; t < 8; ++t) {
        int n = tok0 + t;
        float my = s_lds[n];                      // broadcast: free
        int cnt = 0;
#pragma unroll
        for (int i = 0; i < 4; ++i) {
            int j4 = i * 64 + lane;               // conflict-free b128 reads
            float4 v = sv[j4];
            int j = j4 * 4;
            cnt += (v.x > my) || (v.x == my && (j + 0) < n);
            cnt += (v.y > my) || (v.y == my && (j + 1) < n);
            cnt += (v.z > my) || (v.z == my && (j + 2) < n);
            cnt += (v.w > my) || (v.w == my && (j + 3) < n);
        }
        cnt = wsumi(cnt);                         // wave-uniform rank
        if (cnt < KK) {                           // wave-uniform branch
            const float4* p = reinterpret_cast<const float4*>(
                x + (size_t)(b * NN + n) * DD) + lane * 2;
            float4 v0 = p[0], v1 = p[1];
            c0.x += v0.x; c0.y += v0.y; c0.z += v0.z; c0.w += v0.w;
            c1.x += v1.x; c1.y += v1.y; c1.z += v1.z; c1.w += v1.w;
        }
    }

    __shared__ float red[4][DD];
    {
        float4* rr = reinterpret_cast<float4*>(&red[wave][lane * 8]);
        rr[0] = c0; rr[1] = c1;
    }
    __syncthreads();
#pragma unroll
    for (int i = 0; i < 2; ++i) {
        int d = tid + i * 256;
        float v = red[0][d] + red[1][d] + red[2][d] + red[3][d];
        atomicAdd(&out[b * DD + d], v * (1.0f / (float)KK));   // 32 adds/addr
    }
}

extern "C" void kernel_launch(void* const* d_in, const int* in_sizes, int n_in,
                              void* d_out, int out_size, void* d_ws, size_t ws_size,
                              hipStream_t stream) {
    const float* x = (const float*)d_in[0];
    float* out = (float*)d_out;

    float* ws = (float*)d_ws;
    float* partials = ws;                               // 2048*512 = 4 MB
    float* scores   = ws + BB * CPB1 * DD;              // BB*NN = 128 KB
    float* norms    = ws + BB * CPB1 * DD + BB * NN;    // BB*NN = 128 KB

    k1_norms_partials<<<dim3(BB * CPB1), dim3(256), 0, stream>>>(x, norms, partials);
    k2_scores<<<dim3(BB * CPB2), dim3(256), 0, stream>>>(x, norms, partials, scores, out);
    k34_select_gather<<<dim3(BB * 32), dim3(256), 0, stream>>>(x, scores, out);
}